// Round 10
// baseline (297115.430 us; speedup 1.0000x reference)
//
#include <hip/hip_runtime.h>

// RnnTagger (f32 in / f32 out): tokens[64*512] i32; emb[50000,256]; W_ih[1536,256];
// W_hh[1536,512]; b_ih[1536]; b_hh[1536]; W_tag[64,512]; b_tag[64].
// d_out f32: tag_logits [64,512,64] then preds [64,512] flat.
//
// f32-faithful MFMA via f16 double-split: x ~= hi + lo/4096 (hi,lo f16); product
// = 3 f16 MFMAs (m += Ah*Wh; s += Al*Wh + Ah*Wl; result = m + s/4096).
//
// R16 = R15 resubmission (R15 died on a harness-level Trio exception; kernel
// audited hang-free) + bounded-spin insurance: fast-path flag poll escalates
// to an agent-scope load after ~4k backoff rounds (monotonic accept => safe).
//
// R15: XCD-local exchange. R14's null (AGPR-resident W_hh hi, stream removed,
// FETCH unchanged, dur unchanged) proved the W stream is NOT critical; R11's
// elasticity showed bytes aren't either. Remaining stall = serialized
// agent-scope (sc0 sc1 -> L3) round trips: store-ack drain + flag hop + payload
// RT ~ 4-6us/step. Fix: put each cluster's 8 WGs on ONE XCD and use sc0-only
// ops (L1-bypass, served by the shared per-XCD L2, ~250cy vs ~900cy):
//  - launch 64 WGs; worker iff (bid&7)<4: cluster=bid&7, jg=bid>>3. Under the
//    documented round-robin dispatch (bid%8 -> XCD), cluster c's 8 WGs all
//    land on XCD c. Non-workers exit immediately.
//  - placement is formally undefined (G16), so each cluster RUNTIME-VERIFIES
//    co-location via HW_REG_XCC_ID published through agent-scope slots; only
//    if all 8 match does it enable the sc0 fast path, else it runs the R11
//    agent-scope path unchanged (correct under any placement).
//  - all fast-path asm loads carry s_waitcnt INSIDE the same asm block with
//    early-clobber outputs (R10 NaN lesson); explicit vmcnt(0) drain before
//    the barrier that precedes the flag store.
// Everything else = R11 (512-thr WGs, wave-pair K-split, 4B pk flag-only
// exchange, de-packed LDS h planes, flags in d_out's preds region).
//
// ws (72,482,816 B):
//   [0,+262144)         h pk dbuf  u32[2][64][512]
//   [524288,+3145728)   whh2  [hi/lo][1536][512] f16
//   [3670016,+1572864)  wih2  [hi/lo][1536][256] f16
//   [5242880,+131072)   wtag2 [hi/lo][64][512] f16
//   [5373952,+67108864) st    [b*512+t][512] f32

typedef unsigned short ushortT;
typedef unsigned long long u64c;
typedef float f32x4 __attribute__((ext_vector_type(4)));
typedef _Float16 f16x8 __attribute__((ext_vector_type(8)));
typedef unsigned int u32x4 __attribute__((ext_vector_type(4)));

#define MFMAH(a, b, c) __builtin_amdgcn_mfma_f32_16x16x32_f16((a), (b), (c), 0, 0, 0)
#define KSC (1.0f / 4096.0f)

__device__ __forceinline__ void splitf(float x, ushortT& hi, ushortT& lo) {
    _Float16 h = (_Float16)x;
    float r = x - (float)h;
    _Float16 l = (_Float16)(r * 4096.0f);
    hi = __builtin_bit_cast(ushortT, h);
    lo = __builtin_bit_cast(ushortT, l);
}

// ---------- k0: split weights into f16 hi/lo planes ----------
__global__ __launch_bounds__(256) void split_weights(
    const float* __restrict__ Whh, const float* __restrict__ Wih,
    const float* __restrict__ Wtag, ushortT* __restrict__ wh2,
    ushortT* __restrict__ wi2, ushortT* __restrict__ wt2)
{
    const int i = blockIdx.x * 256 + threadIdx.x;
    ushortT hi, lo;
    if (i < 786432) {                       // 1536*512
        splitf(Whh[i], hi, lo);
        wh2[i] = hi; wh2[786432 + i] = lo;
    } else if (i < 786432 + 393216) {       // 1536*256
        const int j = i - 786432;
        splitf(Wih[j], hi, lo);
        wi2[j] = hi; wi2[393216 + j] = lo;
    } else if (i < 786432 + 393216 + 32768) {   // 64*512
        const int j = i - 786432 - 393216;
        splitf(Wtag[j], hi, lo);
        wt2[j] = hi; wt2[32768 + j] = lo;
    }
}

// ---------- k1: zero h pk double buffer + flags/xcc region ----------
__global__ void init_ws(uint4* p, uint4* f) {
    int i = blockIdx.x * blockDim.x + threadIdx.x;
    uint4 z; z.x = 0u; z.y = 0u; z.z = 0u; z.w = 0u;
    if (i < 16384) p[i] = z;    // 262144 B / 16
    if (i < 512)   f[i] = z;    // 8192 B: flags (4KB) + xcc publish (4KB)
}

// ---------- k2: fused gi + serial GRU recurrence ----------
// 64 WGs x 512; workers = 32 ((bid&7)<4): cluster=bid&7 (== target XCD under
// round-robin), jg=bid>>3 owns h-cols [jg*64,+64). Wave pair (w, w+4) owns
// cols jg*64 + w*16 + [0,16), K-split across the pair.
__global__ __launch_bounds__(512, 1) void gru_rec(
    const int* __restrict__ tok, const float* __restrict__ emb,
    const ushortT* __restrict__ wih2, const ushortT* __restrict__ whh2,
    const float* __restrict__ bih, const float* __restrict__ bhh,
    unsigned* __restrict__ hb32, float* __restrict__ st,
    unsigned* __restrict__ flags)
{
    __shared__ ushortT xl[2][2][16][264];   // 33792 B: x dbuf
    __shared__ ushortT hlh[16 * 520];       // 16640 B: h hi plane
    __shared__ ushortT hll[16 * 520];       // 16640 B: h lo plane
    __shared__ f32x4 pl[4][8][64];          // 32768 B: upper-wave partials
    __shared__ unsigned xs[8];              // xcc verification scratch

    const int bid = blockIdx.x;
    if ((bid & 7) >= 4) return;             // idle WGs (XCDs 4-7) exit
    const int cluster = bid & 7;            // 0..3
    const int jg = bid >> 3;                // 0..7
    const int tid = threadIdx.x;
    const int wave = tid >> 6;
    const int lane = tid & 63;
    const int wl = wave & 3;
    const bool upper = wave >= 4;
    const int ln = lane & 15, quad = lane >> 4;
    const int m0 = cluster * 16;
    const int j_lane = jg * 64 + wl * 16 + ln;

    // 128B-padded flags: flags[(cluster*8 + jg)*32]; threads 0..7 poll.
    unsigned* ownp = flags + (unsigned)(cluster * 8 + jg) * 32u;

    // ---- co-location verification (per cluster) ----
    unsigned xcc = 0;
    asm("s_getreg_b32 %0, hwreg(HW_REG_XCC_ID)" : "=s"(xcc));
    unsigned* xpub = flags + 1024;          // byte offset +4096, zero-init'd
    if (tid == 0)
        __hip_atomic_store(xpub + (unsigned)(cluster * 8 + jg) * 32u, xcc + 1u,
                           __ATOMIC_RELAXED, __HIP_MEMORY_SCOPE_AGENT);
    if (tid < 8) {
        unsigned v2;
        for (;;) {
            v2 = __hip_atomic_load(xpub + (unsigned)(cluster * 8 + tid) * 32u,
                                   __ATOMIC_RELAXED, __HIP_MEMORY_SCOPE_AGENT);
            if (v2) break;
            __builtin_amdgcn_s_sleep(2);
        }
        xs[tid] = v2;
    }
    __syncthreads();
    bool fp = true;
#pragma unroll
    for (int i = 0; i < 8; ++i) fp &= (xs[i] == xs[0]);
    const bool fastp = fp;                  // WG-uniform

    const float c_r  = bih[j_lane]        + bhh[j_lane];
    const float c_z  = bih[512 + j_lane]  + bhh[512 + j_lane];
    const float bi_n = bih[1024 + j_lane];
    const float bh_n = bhh[1024 + j_lane];

    const int fks0 = upper ? 8 : 0;
    const int cks0 = upper ? 4 : 0;

    // Prologue: upper 256 threads stage x_0 into LDS buf 0.
    const int xr = (tid & 255) >> 4, xc = (tid & 15) * 16;
    if (upper) {
        const int token = tok[(m0 + xr) * 512];
        const float* xsrc = emb + (size_t)token * 256 + xc;
#pragma unroll
        for (int i = 0; i < 16; ++i) {
            ushortT hi, lo; splitf(xsrc[i], hi, lo);
            xl[0][0][xr][xc + i] = hi; xl[0][1][xr][xc + i] = lo;
        }
    }
    __syncthreads();

    float hprev[4] = {0.f, 0.f, 0.f, 0.f};

    for (int t = 0; t < 512; ++t) {
        const int rb = t & 1;
        const int wb = rb ^ 1;
        const u64c* tile64 =
            (const u64c*)(hb32 + (size_t)rb * 32768 + (size_t)m0 * 512);

        // (B) upper: x_{t+1} global loads into regs (published in phase H)
        f32x4 xv[4];
        if (upper) {
            const int tp = (t + 1) & 511;
            const int xtoken = tok[(m0 + xr) * 512 + tp];
            const float* xsrc = emb + (size_t)xtoken * 256 + xc;
#pragma unroll
            for (int i = 0; i < 4; ++i)
                xv[i] = *reinterpret_cast<const f32x4*>(xsrc + i * 4);
        }

        f32x4 m_r = (f32x4){0.f,0.f,0.f,0.f}, s_r = (f32x4){0.f,0.f,0.f,0.f};
        f32x4 m_z = (f32x4){0.f,0.f,0.f,0.f}, s_z = (f32x4){0.f,0.f,0.f,0.f};
        f32x4 m_gin = (f32x4){0.f,0.f,0.f,0.f}, s_gin = (f32x4){0.f,0.f,0.f,0.f};
        f32x4 m_ghn = (f32x4){0.f,0.f,0.f,0.f}, s_ghn = (f32x4){0.f,0.f,0.f,0.f};

        // (C) gi = x_t @ W_ih^T, K-split: lower ks 0..3, upper ks 4..7
#pragma unroll
        for (int ksi = 0; ksi < 4; ++ksi) {
            const int k = (cks0 + ksi) * 32 + quad * 8;
            f16x8 Axh = *reinterpret_cast<const f16x8*>(&xl[rb][0][ln][k]);
            f16x8 Axl = *reinterpret_cast<const f16x8*>(&xl[rb][1][ln][k]);
#pragma unroll
            for (int g = 0; g < 3; ++g) {
                const ushortT* wr = wih2 + (size_t)(g * 512 + j_lane) * 256 + k;
                f16x8 Wh = *reinterpret_cast<const f16x8*>(wr);
                f16x8 Wl = *reinterpret_cast<const f16x8*>(wr + 393216);
                if (g == 0) {
                    m_r = MFMAH(Axh, Wh, m_r);
                    s_r = MFMAH(Axl, Wh, s_r);
                    s_r = MFMAH(Axh, Wl, s_r);
                } else if (g == 1) {
                    m_z = MFMAH(Axh, Wh, m_z);
                    s_z = MFMAH(Axl, Wh, s_z);
                    s_z = MFMAH(Axh, Wl, s_z);
                } else {
                    m_gin = MFMAH(Axh, Wh, m_gin);
                    s_gin = MFMAH(Axl, Wh, s_gin);
                    s_gin = MFMAH(Axh, Wl, s_gin);
                }
            }
        }

        // (D0) flag wait: threads 0..7 each spin on one producer flag.
        // Fast path: sc0 (XCD-L2) loads; escalate to agent-scope after ~4k
        // rounds as hang insurance (accept is monotonic -> always safe).
        if (tid < 8) {
            const unsigned want = (unsigned)t;
            unsigned* pp = flags + (unsigned)(cluster * 8 + tid) * 32u;
            if (fastp) {
                unsigned f;
                int spins = 0;
                for (;;) {
                    asm volatile("global_load_dword %0, %1, off sc0\n\t"
                                 "s_waitcnt vmcnt(0)"
                                 : "=&v"(f) : "v"(pp) : "memory");
                    if (f >= want) break;
                    if (++spins > 4096) {
                        f = __hip_atomic_load(pp, __ATOMIC_RELAXED,
                                              __HIP_MEMORY_SCOPE_AGENT);
                        if (f >= want) break;
                    }
                    __builtin_amdgcn_s_sleep(2);
                }
            } else {
                unsigned f = __hip_atomic_load(pp, __ATOMIC_RELAXED,
                                               __HIP_MEMORY_SCOPE_AGENT);
                while (f < want) {
                    __builtin_amdgcn_s_sleep(2);
                    f = __hip_atomic_load(pp, __ATOMIC_RELAXED,
                                          __HIP_MEMORY_SCOPE_AGENT);
                }
            }
        }
        __syncthreads();   // all 8 producer flags confirmed across the WG

        // (A) payload read: 8 u64 per thread (two pk's each).
        u64c v[8];
        if (fastp) {
            const u64c* b = tile64 + tid;
            asm volatile(
                "global_load_dwordx2 %0, %8, off sc0\n\t"
                "global_load_dwordx2 %1, %9, off sc0\n\t"
                "global_load_dwordx2 %2, %10, off sc0\n\t"
                "global_load_dwordx2 %3, %11, off sc0\n\t"
                "global_load_dwordx2 %4, %12, off sc0\n\t"
                "global_load_dwordx2 %5, %13, off sc0\n\t"
                "global_load_dwordx2 %6, %14, off sc0\n\t"
                "global_load_dwordx2 %7, %15, off sc0\n\t"
                "s_waitcnt vmcnt(0)"
                : "=&v"(v[0]), "=&v"(v[1]), "=&v"(v[2]), "=&v"(v[3]),
                  "=&v"(v[4]), "=&v"(v[5]), "=&v"(v[6]), "=&v"(v[7])
                : "v"(b), "v"(b + 512), "v"(b + 1024), "v"(b + 1536),
                  "v"(b + 2048), "v"(b + 2560), "v"(b + 3072), "v"(b + 3584)
                : "memory");
        } else {
#pragma unroll
            for (int j = 0; j < 8; ++j)
                v[j] = __hip_atomic_load(tile64 + tid + 512 * j,
                                         __ATOMIC_RELAXED, __HIP_MEMORY_SCOPE_AGENT);
        }

        // (E) publish DE-PACKED hi/lo planes to LDS: 2 cols per atom
#pragma unroll
        for (int j = 0; j < 8; ++j) {
            const int a = tid + 512 * j;
            const int row = a >> 8;
            const int c2 = (a & 255) * 2;
            const unsigned lo32 = (unsigned)v[j];
            const unsigned hi32 = (unsigned)(v[j] >> 32);
            *reinterpret_cast<unsigned*>(&hlh[row * 520 + c2]) =
                (lo32 & 0xffffu) | (hi32 << 16);
            *reinterpret_cast<unsigned*>(&hll[row * 520 + c2]) =
                (lo32 >> 16) | (hi32 & 0xffff0000u);
        }
        __syncthreads();

        // (F) gh = h_{t-1} @ W_hh^T, K-split: lower ks 0..7, upper ks 8..15.
#pragma unroll
        for (int ksi = 0; ksi < 8; ++ksi) {
            const int k = (fks0 + ksi) * 32 + quad * 8;
            f16x8 Ah = *reinterpret_cast<const f16x8*>(&hlh[ln * 520 + k]);
            f16x8 Al = *reinterpret_cast<const f16x8*>(&hll[ln * 520 + k]);
#pragma unroll
            for (int g = 0; g < 3; ++g) {
                const ushortT* wr = whh2 + (size_t)(g * 512 + j_lane) * 512 + k;
                f16x8 Wh = *reinterpret_cast<const f16x8*>(wr);
                f16x8 Wl = *reinterpret_cast<const f16x8*>(wr + 786432);
                if (g == 0) {
                    m_r = MFMAH(Ah, Wh, m_r);
                    s_r = MFMAH(Al, Wh, s_r);
                    s_r = MFMAH(Ah, Wl, s_r);
                } else if (g == 1) {
                    m_z = MFMAH(Ah, Wh, m_z);
                    s_z = MFMAH(Al, Wh, s_z);
                    s_z = MFMAH(Ah, Wl, s_z);
                } else {
                    m_ghn = MFMAH(Ah, Wh, m_ghn);
                    s_ghn = MFMAH(Al, Wh, s_ghn);
                    s_ghn = MFMAH(Ah, Wl, s_ghn);
                }
            }
        }

        // (R) upper waves dump partials to LDS
        if (upper) {
            const int u = wave - 4;
            pl[u][0][lane] = m_r;   pl[u][1][lane] = s_r;
            pl[u][2][lane] = m_z;   pl[u][3][lane] = s_z;
            pl[u][4][lane] = m_gin; pl[u][5][lane] = s_gin;
            pl[u][6][lane] = m_ghn; pl[u][7][lane] = s_ghn;
        }
        __syncthreads();

        float hn4[4];
        if (!upper) {
            m_r   += pl[wave][0][lane]; s_r   += pl[wave][1][lane];
            m_z   += pl[wave][2][lane]; s_z   += pl[wave][3][lane];
            m_gin += pl[wave][4][lane]; s_gin += pl[wave][5][lane];
            m_ghn += pl[wave][6][lane]; s_ghn += pl[wave][7][lane];

            // (G) gates + h_new; pk stores via fast (sc0) or agent path
            unsigned* hw32 = hb32 + (size_t)wb * 32768;
            unsigned pk4[4];
            unsigned* sa0; unsigned* sa1; unsigned* sa2; unsigned* sa3;
#pragma unroll
            for (int r4 = 0; r4 < 4; ++r4) {
                const float pre_r = m_r[r4] + s_r[r4] * KSC + c_r;
                const float pre_z = m_z[r4] + s_z[r4] * KSC + c_z;
                const float gin   = m_gin[r4] + s_gin[r4] * KSC + bi_n;
                const float ghn   = m_ghn[r4] + s_ghn[r4] * KSC + bh_n;
                const float rr = 1.f / (1.f + expf(-pre_r));
                const float zz = 1.f / (1.f + expf(-pre_z));
                const float nn = tanhf(gin + rr * ghn);
                const float hn = (1.f - zz) * nn + zz * hprev[r4];
                hprev[r4] = hn;
                hn4[r4] = hn;
                ushortT hi, lo; splitf(hn, hi, lo);
                pk4[r4] = (unsigned)hi | ((unsigned)lo << 16);
            }
            sa0 = hw32 + (m0 + quad * 4 + 0) * 512 + j_lane;
            sa1 = hw32 + (m0 + quad * 4 + 1) * 512 + j_lane;
            sa2 = hw32 + (m0 + quad * 4 + 2) * 512 + j_lane;
            sa3 = hw32 + (m0 + quad * 4 + 3) * 512 + j_lane;
            if (fastp) {
                asm volatile(
                    "global_store_dword %4, %0, off sc0\n\t"
                    "global_store_dword %5, %1, off sc0\n\t"
                    "global_store_dword %6, %2, off sc0\n\t"
                    "global_store_dword %7, %3, off sc0"
                    :
                    : "v"(pk4[0]), "v"(pk4[1]), "v"(pk4[2]), "v"(pk4[3]),
                      "v"(sa0), "v"(sa1), "v"(sa2), "v"(sa3)
                    : "memory");
            } else {
                __hip_atomic_store(sa0, pk4[0], __ATOMIC_RELAXED, __HIP_MEMORY_SCOPE_AGENT);
                __hip_atomic_store(sa1, pk4[1], __ATOMIC_RELAXED, __HIP_MEMORY_SCOPE_AGENT);
                __hip_atomic_store(sa2, pk4[2], __ATOMIC_RELAXED, __HIP_MEMORY_SCOPE_AGENT);
                __hip_atomic_store(sa3, pk4[3], __ATOMIC_RELAXED, __HIP_MEMORY_SCOPE_AGENT);
            }
        } else {
            // (H) publish x_{t+1} into LDS buffer wb
#pragma unroll
            for (int i = 0; i < 16; ++i) {
                ushortT hi, lo; splitf(xv[i >> 2][i & 3], hi, lo);
                xl[wb][0][xr][xc + i] = hi; xl[wb][1][xr][xc + i] = lo;
            }
        }

        // explicit drain: asm stores aren't tracked by the compiler's waitcnt
        // insertion, so force vmcnt(0) before the barrier -> flag ordering.
        asm volatile("s_waitcnt vmcnt(0)" ::: "memory");
        __syncthreads();
        if (tid == 0) {
            const unsigned nf = (unsigned)(t + 1);
            if (fastp)
                asm volatile("global_store_dword %1, %0, off sc0"
                             :: "v"(nf), "v"(ownp) : "memory");
            else
                __hip_atomic_store(ownp, nf, __ATOMIC_RELAXED,
                                   __HIP_MEMORY_SCOPE_AGENT);
        }

        // st stores — consumed only by k3 after this kernel; off critical path
        if (!upper) {
#pragma unroll
            for (int r4 = 0; r4 < 4; ++r4) {
                const int b = m0 + quad * 4 + r4;
                st[((size_t)b * 512 + t) * 512 + j_lane] = hn4[r4];
            }
        }
    }
}

// ---------- k3: tag logits + argmax + PAD mask (R5-identical) ----------
__global__ __launch_bounds__(256) void tag_argmax(
    const float* __restrict__ st, const ushortT* __restrict__ wtag2,
    const float* __restrict__ btag, const int* __restrict__ tok,
    float* __restrict__ out)
{
    const int wave = threadIdx.x >> 6;
    const int lane = threadIdx.x & 63;
    const int ln = lane & 15, quad = lane >> 4;
    const int mt = blockIdx.x * 4 + wave;   // 0..2047

    const float* arow = st + (size_t)(mt * 16 + ln) * 512;
    f32x4 am[4], as_[4];
#pragma unroll
    for (int ti = 0; ti < 4; ++ti) { am[ti] = (f32x4){0.f,0.f,0.f,0.f}; as_[ti] = (f32x4){0.f,0.f,0.f,0.f}; }

#pragma unroll
    for (int ks = 0; ks < 16; ++ks) {
        const int k = ks * 32 + quad * 8;
        f16x8 Ah, Al;
#pragma unroll
        for (int e = 0; e < 8; ++e) {
            const float x = arow[k + e];
            _Float16 h = (_Float16)x;
            Ah[e] = h;
            Al[e] = (_Float16)((x - (float)h) * 4096.0f);
        }
#pragma unroll
        for (int ti = 0; ti < 4; ++ti) {
            const ushortT* wr = wtag2 + (size_t)(ti * 16 + ln) * 512 + k;
            f16x8 Wh = *reinterpret_cast<const f16x8*>(wr);
            f16x8 Wl = *reinterpret_cast<const f16x8*>(wr + 32768);
            am[ti]  = MFMAH(Ah, Wh, am[ti]);
            as_[ti] = MFMAH(Ah, Wl, as_[ti]);
            as_[ti] = MFMAH(Al, Wh, as_[ti]);
        }
    }

    float vals[4][4];
#pragma unroll
    for (int ti = 0; ti < 4; ++ti) {
        const float bb = btag[ti * 16 + ln];
#pragma unroll
        for (int r = 0; r < 4; ++r) vals[ti][r] = am[ti][r] + as_[ti][r] * KSC + bb;
    }
#pragma unroll
    for (int ti = 0; ti < 4; ++ti)
#pragma unroll
        for (int r = 0; r < 4; ++r) {
            const int row = mt * 16 + quad * 4 + r;
            out[(size_t)row * 64 + ti * 16 + ln] = vals[ti][r];
        }
#pragma unroll
    for (int r = 0; r < 4; ++r) {
        float best = vals[0][r];
        int bc = ln;
#pragma unroll
        for (int ti = 1; ti < 4; ++ti) {
            const float v = vals[ti][r];
            const int c = ti * 16 + ln;
            if (v > best) { best = v; bc = c; }
        }
        for (int off = 1; off < 16; off <<= 1) {
            const float ov = __shfl_xor(best, off);
            const int oc = __shfl_xor(bc, off);
            if (ov > best || (ov == best && oc < bc)) { best = ov; bc = oc; }
        }
        if (ln == 0) {
            const int row = mt * 16 + quad * 4 + r;   // = b*512+t = token idx
            const int token = tok[row];
            const int pred = (token != 0) ? bc : 0;
            out[2097152 + (size_t)row] = (float)pred;
        }
    }
}

extern "C" void kernel_launch(void* const* d_in, const int* in_sizes, int n_in,
                              void* d_out, int out_size, void* d_ws, size_t ws_size,
                              hipStream_t stream) {
    const int*   tokens = (const int*)d_in[0];
    const float* emb    = (const float*)d_in[1];
    const float* Wih    = (const float*)d_in[2];
    const float* Whh    = (const float*)d_in[3];
    const float* bih    = (const float*)d_in[4];
    const float* bhh    = (const float*)d_in[5];
    const float* Wtag   = (const float*)d_in[6];
    const float* btag   = (const float*)d_in[7];

    char* ws = (char*)d_ws;
    unsigned* hb32  = (unsigned*)ws;                 // 262,144 B used
    ushortT*  whh2  = (ushortT*)(ws + 524288);       // 3,145,728 B
    ushortT*  wih2  = (ushortT*)(ws + 3670016);      // 1,572,864 B
    ushortT*  wtag2 = (ushortT*)(ws + 5242880);      // 131,072 B
    float*    stf   = (float*)(ws + 5373952);        // 67,108,864 B (total 72.48 MB)
    float*    out   = (float*)d_out;

    // Sync flags + xcc-publish live in d_out's preds region (scratch during
    // gru_rec; tag_argmax rewrites every preds element afterwards).
    unsigned* flags = (unsigned*)(out + 2097152);

    split_weights<<<4736, 256, 0, stream>>>(Whh, Wih, Wtag, whh2, wih2, wtag2);
    init_ws<<<128, 256, 0, stream>>>((uint4*)ws, (uint4*)flags);
    gru_rec<<<64, 512, 0, stream>>>(tokens, emb, wih2, whh2, bih, bhh, hb32, stf, flags);
    tag_argmax<<<512, 256, 0, stream>>>(stf, wtag2, btag, tokens, out);
}

// Round 11
// 7387.619 us; speedup vs baseline: 40.2180x; 40.2180x over previous
//
#include <hip/hip_runtime.h>

// RnnTagger (f32 in / f32 out): tokens[64*512] i32; emb[50000,256]; W_ih[1536,256];
// W_hh[1536,512]; b_ih[1536]; b_hh[1536]; W_tag[64,512]; b_tag[64].
// d_out f32: tag_logits [64,512,64] then preds [64,512] flat.
//
// f32-faithful MFMA via f16 double-split: x ~= hi + lo/4096 (hi,lo f16); product
// = 3 f16 MFMAs (m += Ah*Wh; s += Al*Wh + Ah*Wl; result = m + s/4096).
//
// R17 = R11 base (best verified, 6481us) + shortened producer->consumer spine.
// R16 post-mortem: sc0-only loads are NOT L1-coherent (consumer spun 4096
// rounds on a stale L1 line every step -> 650us/step; agent escalation
// rescued). XCD-local sc-bit exchange abandoned. R14 proved W-streams are
// off-path; R11 proved bytes are no longer dominant. Remaining lever: the
// flag was published only after a full-WG barrier (waits all 8 waves incl.
// upper's x-publish). R17:
//  - PER-WAVE FLAGS: each lower wave, right after its 4 pk stores, does a
//    wave-level s_waitcnt vmcnt(0) (covers all 64 lanes' stores) and lane 0
//    publishes flag[cluster][jg][wave]=t+1 (agent scope). No barrier on the
//    flag path. Consumers poll 32 slots (threads 0..31, one each).
//  - end-of-loop __syncthreads kept (xl/hl/pl turnover only).
//  - fast gates: __expf-based sigmoid/tanh (correct saturation at +-inf).
// Everything else = R11 (512-thr WGs, wave-pair K-split, 4B pk flag-only
// exchange, u64 agent atomic payload reads, de-packed LDS h planes, flags in
// d_out's preds region).
//
// ws (72,482,816 B):
//   [0,+262144)         h pk dbuf  u32[2][64][512]
//   [524288,+3145728)   whh2  [hi/lo][1536][512] f16
//   [3670016,+1572864)  wih2  [hi/lo][1536][256] f16
//   [5242880,+131072)   wtag2 [hi/lo][64][512] f16
//   [5373952,+67108864) st    [b*512+t][512] f32

typedef unsigned short ushortT;
typedef unsigned long long u64c;
typedef float f32x4 __attribute__((ext_vector_type(4)));
typedef _Float16 f16x8 __attribute__((ext_vector_type(8)));
typedef unsigned int u32x4 __attribute__((ext_vector_type(4)));

#define MFMAH(a, b, c) __builtin_amdgcn_mfma_f32_16x16x32_f16((a), (b), (c), 0, 0, 0)
#define KSC (1.0f / 4096.0f)

__device__ __forceinline__ void splitf(float x, ushortT& hi, ushortT& lo) {
    _Float16 h = (_Float16)x;
    float r = x - (float)h;
    _Float16 l = (_Float16)(r * 4096.0f);
    hi = __builtin_bit_cast(ushortT, h);
    lo = __builtin_bit_cast(ushortT, l);
}

__device__ __forceinline__ float fsigmoid(float x) {
    return 1.0f / (1.0f + __expf(-x));     // x->-inf: exp(inf)=inf -> 0; ok
}
__device__ __forceinline__ float ftanh(float x) {
    const float e2 = __expf(2.0f * x);     // x->+inf: inf -> 1; x->-inf: 0 -> -1
    return 1.0f - 2.0f / (e2 + 1.0f);
}

// ---------- k0: split weights into f16 hi/lo planes ----------
__global__ __launch_bounds__(256) void split_weights(
    const float* __restrict__ Whh, const float* __restrict__ Wih,
    const float* __restrict__ Wtag, ushortT* __restrict__ wh2,
    ushortT* __restrict__ wi2, ushortT* __restrict__ wt2)
{
    const int i = blockIdx.x * 256 + threadIdx.x;
    ushortT hi, lo;
    if (i < 786432) {                       // 1536*512
        splitf(Whh[i], hi, lo);
        wh2[i] = hi; wh2[786432 + i] = lo;
    } else if (i < 786432 + 393216) {       // 1536*256
        const int j = i - 786432;
        splitf(Wih[j], hi, lo);
        wi2[j] = hi; wi2[393216 + j] = lo;
    } else if (i < 786432 + 393216 + 32768) {   // 64*512
        const int j = i - 786432 - 393216;
        splitf(Wtag[j], hi, lo);
        wt2[j] = hi; wt2[32768 + j] = lo;
    }
}

// ---------- k1: zero h pk double buffer + flags ----------
__global__ void init_ws(uint4* p, uint4* f) {
    int i = blockIdx.x * blockDim.x + threadIdx.x;
    uint4 z; z.x = 0u; z.y = 0u; z.z = 0u; z.w = 0u;
    if (i < 16384) p[i] = z;    // 262144 B / 16
    if (i < 256)   f[i] = z;    // 4096 B of flags
}

// ---------- k2: fused gi + serial GRU recurrence ----------
// 32 WGs x 512 (8 waves = 2 waves/SIMD). cluster = bid>>3 owns batch rows
// [cluster*16,+16); jg = bid&7 owns h-cols [jg*64,+64). Wave pair (w, w+4)
// owns cols jg*64 + w*16 + [0,16), K-split across the pair.
__global__ __launch_bounds__(512, 1) void gru_rec(
    const int* __restrict__ tok, const float* __restrict__ emb,
    const ushortT* __restrict__ wih2, const ushortT* __restrict__ whh2,
    const float* __restrict__ bih, const float* __restrict__ bhh,
    unsigned* __restrict__ hb32, float* __restrict__ st,
    unsigned* __restrict__ flags)
{
    __shared__ ushortT xl[2][2][16][264];   // 33792 B: x dbuf [buf][hi/lo][16 b][256k pad]
    __shared__ ushortT hlh[16 * 520];       // 16640 B: h hi plane [16 rows][512 + pad 8]
    __shared__ ushortT hll[16 * 520];       // 16640 B: h lo plane
    __shared__ f32x4 pl[4][8][64];          // 32768 B: upper-wave partials [u][vec][lane]

    const int bid = blockIdx.x;
    const int cluster = bid >> 3;
    const int jg = bid & 7;
    const int tid = threadIdx.x;
    const int wave = tid >> 6;
    const int lane = tid & 63;
    const int wl = wave & 3;                // pair column-slot 0..3
    const bool upper = wave >= 4;
    const int ln = lane & 15, quad = lane >> 4;
    const int m0 = cluster * 16;
    const int j_lane = jg * 64 + wl * 16 + ln;

    // 128B-padded per-WG flag block: flags[(cluster*8 + jg)*32 + waveslot],
    // waveslot 0..3 = lower waves. Threads 0..31 poll (jg=tid>>2, slot=tid&3).
    unsigned* ownp = flags + (unsigned)(cluster * 8 + jg) * 32u + (unsigned)wl;

    const float c_r  = bih[j_lane]        + bhh[j_lane];
    const float c_z  = bih[512 + j_lane]  + bhh[512 + j_lane];
    const float bi_n = bih[1024 + j_lane];
    const float bh_n = bhh[1024 + j_lane];

    const int fks0 = upper ? 8 : 0;
    const int cks0 = upper ? 4 : 0;

    // Prologue: upper 256 threads stage x_0 into LDS buf 0.
    const int xr = (tid & 255) >> 4, xc = (tid & 15) * 16;
    if (upper) {
        const int token = tok[(m0 + xr) * 512];
        const float* xsrc = emb + (size_t)token * 256 + xc;
#pragma unroll
        for (int i = 0; i < 16; ++i) {
            ushortT hi, lo; splitf(xsrc[i], hi, lo);
            xl[0][0][xr][xc + i] = hi; xl[0][1][xr][xc + i] = lo;
        }
    }
    __syncthreads();

    float hprev[4] = {0.f, 0.f, 0.f, 0.f};

    for (int t = 0; t < 512; ++t) {
        const int rb = t & 1;
        const int wb = rb ^ 1;
        const u64c* tile64 =
            (const u64c*)(hb32 + (size_t)rb * 32768 + (size_t)m0 * 512);

        // (B) upper: x_{t+1} global loads into regs (published in phase H)
        f32x4 xv[4];
        if (upper) {
            const int tp = (t + 1) & 511;
            const int xtoken = tok[(m0 + xr) * 512 + tp];
            const float* xsrc = emb + (size_t)xtoken * 256 + xc;
#pragma unroll
            for (int i = 0; i < 4; ++i)
                xv[i] = *reinterpret_cast<const f32x4*>(xsrc + i * 4);
        }

        // per-pair partial accumulators
        f32x4 m_r = (f32x4){0.f,0.f,0.f,0.f}, s_r = (f32x4){0.f,0.f,0.f,0.f};
        f32x4 m_z = (f32x4){0.f,0.f,0.f,0.f}, s_z = (f32x4){0.f,0.f,0.f,0.f};
        f32x4 m_gin = (f32x4){0.f,0.f,0.f,0.f}, s_gin = (f32x4){0.f,0.f,0.f,0.f};
        f32x4 m_ghn = (f32x4){0.f,0.f,0.f,0.f}, s_ghn = (f32x4){0.f,0.f,0.f,0.f};

        // (C) gi = x_t @ W_ih^T, K-split: lower ks 0..3, upper ks 4..7
#pragma unroll
        for (int ksi = 0; ksi < 4; ++ksi) {
            const int k = (cks0 + ksi) * 32 + quad * 8;
            f16x8 Axh = *reinterpret_cast<const f16x8*>(&xl[rb][0][ln][k]);
            f16x8 Axl = *reinterpret_cast<const f16x8*>(&xl[rb][1][ln][k]);
#pragma unroll
            for (int g = 0; g < 3; ++g) {
                const ushortT* wr = wih2 + (size_t)(g * 512 + j_lane) * 256 + k;
                f16x8 Wh = *reinterpret_cast<const f16x8*>(wr);
                f16x8 Wl = *reinterpret_cast<const f16x8*>(wr + 393216);
                if (g == 0) {
                    m_r = MFMAH(Axh, Wh, m_r);
                    s_r = MFMAH(Axl, Wh, s_r);
                    s_r = MFMAH(Axh, Wl, s_r);
                } else if (g == 1) {
                    m_z = MFMAH(Axh, Wh, m_z);
                    s_z = MFMAH(Axl, Wh, s_z);
                    s_z = MFMAH(Axh, Wl, s_z);
                } else {
                    m_gin = MFMAH(Axh, Wh, m_gin);
                    s_gin = MFMAH(Axl, Wh, s_gin);
                    s_gin = MFMAH(Axh, Wl, s_gin);
                }
            }
        }

        // (D0) flag wait: threads 0..31 each spin on one producer-WAVE flag
        if (tid < 32) {
            const unsigned want = (unsigned)t;
            unsigned* pp = flags + (unsigned)(cluster * 8 + (tid >> 2)) * 32u
                                 + (unsigned)(tid & 3);
            unsigned f = __hip_atomic_load(pp, __ATOMIC_RELAXED,
                                           __HIP_MEMORY_SCOPE_AGENT);
            while (f < want) {
                __builtin_amdgcn_s_sleep(2);
                f = __hip_atomic_load(pp, __ATOMIC_RELAXED,
                                      __HIP_MEMORY_SCOPE_AGENT);
            }
        }
        __syncthreads();   // all 32 producer-wave flags confirmed across the WG

        // (A) payload read: 8 u64 agent-coherent atomic loads per thread,
        // each carrying TWO 4B pk's. Flag-sync guarantees visibility.
        u64c v[8];
#pragma unroll
        for (int j = 0; j < 8; ++j)
            v[j] = __hip_atomic_load(tile64 + tid + 512 * j,
                                     __ATOMIC_RELAXED, __HIP_MEMORY_SCOPE_AGENT);

        // (E) publish DE-PACKED hi/lo planes to LDS: 2 cols per atom,
        // packed u32 writes (4B-aligned since c2 and row stride are even)
#pragma unroll
        for (int j = 0; j < 8; ++j) {
            const int a = tid + 512 * j;        // u64 index in [0,4096)
            const int row = a >> 8;             // 0..15
            const int c2 = (a & 255) * 2;       // 0,2,...,510
            const unsigned lo32 = (unsigned)v[j];
            const unsigned hi32 = (unsigned)(v[j] >> 32);
            *reinterpret_cast<unsigned*>(&hlh[row * 520 + c2]) =
                (lo32 & 0xffffu) | (hi32 << 16);
            *reinterpret_cast<unsigned*>(&hll[row * 520 + c2]) =
                (lo32 >> 16) | (hi32 & 0xffff0000u);
        }
        __syncthreads();

        // (F) gh = h_{t-1} @ W_hh^T, K-split: lower ks 0..7, upper ks 8..15.
        // A-frags: direct b128 from de-packed planes. W: streamed from L2.
#pragma unroll
        for (int ksi = 0; ksi < 8; ++ksi) {
            const int k = (fks0 + ksi) * 32 + quad * 8;
            f16x8 Ah = *reinterpret_cast<const f16x8*>(&hlh[ln * 520 + k]);
            f16x8 Al = *reinterpret_cast<const f16x8*>(&hll[ln * 520 + k]);
#pragma unroll
            for (int g = 0; g < 3; ++g) {
                const ushortT* wr = whh2 + (size_t)(g * 512 + j_lane) * 512 + k;
                f16x8 Wh = *reinterpret_cast<const f16x8*>(wr);
                f16x8 Wl = *reinterpret_cast<const f16x8*>(wr + 786432);
                if (g == 0) {
                    m_r = MFMAH(Ah, Wh, m_r);
                    s_r = MFMAH(Al, Wh, s_r);
                    s_r = MFMAH(Ah, Wl, s_r);
                } else if (g == 1) {
                    m_z = MFMAH(Ah, Wh, m_z);
                    s_z = MFMAH(Al, Wh, s_z);
                    s_z = MFMAH(Ah, Wl, s_z);
                } else {
                    m_ghn = MFMAH(Ah, Wh, m_ghn);
                    s_ghn = MFMAH(Al, Wh, s_ghn);
                    s_ghn = MFMAH(Ah, Wl, s_ghn);
                }
            }
        }

        // (R) upper waves dump partials to LDS (lane-consecutive 16B: conflict-free)
        if (upper) {
            const int u = wave - 4;
            pl[u][0][lane] = m_r;   pl[u][1][lane] = s_r;
            pl[u][2][lane] = m_z;   pl[u][3][lane] = s_z;
            pl[u][4][lane] = m_gin; pl[u][5][lane] = s_gin;
            pl[u][6][lane] = m_ghn; pl[u][7][lane] = s_ghn;
        }
        __syncthreads();

        float hn4[4];
        if (!upper) {
            // combine K-halves
            m_r   += pl[wave][0][lane]; s_r   += pl[wave][1][lane];
            m_z   += pl[wave][2][lane]; s_z   += pl[wave][3][lane];
            m_gin += pl[wave][4][lane]; s_gin += pl[wave][5][lane];
            m_ghn += pl[wave][6][lane]; s_ghn += pl[wave][7][lane];

            // (G) gates + h_new; 4B pk stores, then WAVE-LOCAL drain + flag.
            unsigned* hw32 = hb32 + (size_t)wb * 32768;
#pragma unroll
            for (int r4 = 0; r4 < 4; ++r4) {
                const float pre_r = m_r[r4] + s_r[r4] * KSC + c_r;
                const float pre_z = m_z[r4] + s_z[r4] * KSC + c_z;
                const float gin   = m_gin[r4] + s_gin[r4] * KSC + bi_n;
                const float ghn   = m_ghn[r4] + s_ghn[r4] * KSC + bh_n;
                const float rr = fsigmoid(pre_r);
                const float zz = fsigmoid(pre_z);
                const float nn = ftanh(gin + rr * ghn);
                const float hn = (1.f - zz) * nn + zz * hprev[r4];
                hprev[r4] = hn;
                hn4[r4] = hn;
                ushortT hi, lo; splitf(hn, hi, lo);
                const unsigned pk = (unsigned)hi | ((unsigned)lo << 16);
                const int b = m0 + quad * 4 + r4;
                __hip_atomic_store(&hw32[b * 512 + j_lane], pk,
                                   __ATOMIC_RELAXED, __HIP_MEMORY_SCOPE_AGENT);
            }
            // wave-level drain: s_waitcnt counters are per-wave, so this
            // covers all 64 lanes' pk stores; then lane 0 publishes the flag.
            asm volatile("s_waitcnt vmcnt(0)" ::: "memory");
            if (lane == 0)
                __hip_atomic_store(ownp, (unsigned)(t + 1),
                                   __ATOMIC_RELAXED, __HIP_MEMORY_SCOPE_AGENT);
            // st stores — consumed only by k3 after this kernel; off path
#pragma unroll
            for (int r4 = 0; r4 < 4; ++r4) {
                const int b = m0 + quad * 4 + r4;
                st[((size_t)b * 512 + t) * 512 + j_lane] = hn4[r4];
            }
        } else {
            // (H) publish x_{t+1} into LDS buffer wb
#pragma unroll
            for (int i = 0; i < 16; ++i) {
                ushortT hi, lo; splitf(xv[i >> 2][i & 3], hi, lo);
                xl[wb][0][xr][xc + i] = hi; xl[wb][1][xr][xc + i] = lo;
            }
        }

        // xl + hl + pl turnover only (flags already out, wave-local ordered)
        __syncthreads();
    }
}

// ---------- k3: tag logits + argmax + PAD mask (R5-identical) ----------
__global__ __launch_bounds__(256) void tag_argmax(
    const float* __restrict__ st, const ushortT* __restrict__ wtag2,
    const float* __restrict__ btag, const int* __restrict__ tok,
    float* __restrict__ out)
{
    const int wave = threadIdx.x >> 6;
    const int lane = threadIdx.x & 63;
    const int ln = lane & 15, quad = lane >> 4;
    const int mt = blockIdx.x * 4 + wave;   // 0..2047

    const float* arow = st + (size_t)(mt * 16 + ln) * 512;
    f32x4 am[4], as_[4];
#pragma unroll
    for (int ti = 0; ti < 4; ++ti) { am[ti] = (f32x4){0.f,0.f,0.f,0.f}; as_[ti] = (f32x4){0.f,0.f,0.f,0.f}; }

#pragma unroll
    for (int ks = 0; ks < 16; ++ks) {
        const int k = ks * 32 + quad * 8;
        f16x8 Ah, Al;
#pragma unroll
        for (int e = 0; e < 8; ++e) {
            const float x = arow[k + e];
            _Float16 h = (_Float16)x;
            Ah[e] = h;
            Al[e] = (_Float16)((x - (float)h) * 4096.0f);
        }
#pragma unroll
        for (int ti = 0; ti < 4; ++ti) {
            const ushortT* wr = wtag2 + (size_t)(ti * 16 + ln) * 512 + k;
            f16x8 Wh = *reinterpret_cast<const f16x8*>(wr);
            f16x8 Wl = *reinterpret_cast<const f16x8*>(wr + 32768);
            am[ti]  = MFMAH(Ah, Wh, am[ti]);
            as_[ti] = MFMAH(Ah, Wl, as_[ti]);
            as_[ti] = MFMAH(Al, Wh, as_[ti]);
        }
    }

    float vals[4][4];
#pragma unroll
    for (int ti = 0; ti < 4; ++ti) {
        const float bb = btag[ti * 16 + ln];
#pragma unroll
        for (int r = 0; r < 4; ++r) vals[ti][r] = am[ti][r] + as_[ti][r] * KSC + bb;
    }
#pragma unroll
    for (int ti = 0; ti < 4; ++ti)
#pragma unroll
        for (int r = 0; r < 4; ++r) {
            const int row = mt * 16 + quad * 4 + r;
            out[(size_t)row * 64 + ti * 16 + ln] = vals[ti][r];
        }
#pragma unroll
    for (int r = 0; r < 4; ++r) {
        float best = vals[0][r];
        int bc = ln;
#pragma unroll
        for (int ti = 1; ti < 4; ++ti) {
            const float v = vals[ti][r];
            const int c = ti * 16 + ln;
            if (v > best) { best = v; bc = c; }
        }
        for (int off = 1; off < 16; off <<= 1) {
            const float ov = __shfl_xor(best, off);
            const int oc = __shfl_xor(bc, off);
            if (ov > best || (ov == best && oc < bc)) { best = ov; bc = oc; }
        }
        if (ln == 0) {
            const int row = mt * 16 + quad * 4 + r;   // = b*512+t = token idx
            const int token = tok[row];
            const int pred = (token != 0) ? bc : 0;
            out[2097152 + (size_t)row] = (float)pred;
        }
    }
}

extern "C" void kernel_launch(void* const* d_in, const int* in_sizes, int n_in,
                              void* d_out, int out_size, void* d_ws, size_t ws_size,
                              hipStream_t stream) {
    const int*   tokens = (const int*)d_in[0];
    const float* emb    = (const float*)d_in[1];
    const float* Wih    = (const float*)d_in[2];
    const float* Whh    = (const float*)d_in[3];
    const float* bih    = (const float*)d_in[4];
    const float* bhh    = (const float*)d_in[5];
    const float* Wtag   = (const float*)d_in[6];
    const float* btag   = (const float*)d_in[7];

    char* ws = (char*)d_ws;
    unsigned* hb32  = (unsigned*)ws;                 // 262,144 B used
    ushortT*  whh2  = (ushortT*)(ws + 524288);       // 3,145,728 B
    ushortT*  wih2  = (ushortT*)(ws + 3670016);      // 1,572,864 B
    ushortT*  wtag2 = (ushortT*)(ws + 5242880);      // 131,072 B
    float*    stf   = (float*)(ws + 5373952);        // 67,108,864 B (total 72.48 MB)
    float*    out   = (float*)d_out;

    // Sync flags live in d_out's preds region (scratch during gru_rec;
    // tag_argmax rewrites every preds element afterwards). 32 WG-blocks x
    // 128B; per-wave slots within each block.
    unsigned* flags = (unsigned*)(out + 2097152);

    split_weights<<<4736, 256, 0, stream>>>(Whh, Wih, Wtag, whh2, wih2, wtag2);
    init_ws<<<128, 256, 0, stream>>>((uint4*)ws, (uint4*)flags);
    gru_rec<<<32, 512, 0, stream>>>(tokens, emb, wih2, whh2, bih, bhh, hb32, stf, flags);
    tag_argmax<<<512, 256, 0, stream>>>(stf, wtag2, btag, tokens, out);
}

// Round 12
// 6438.400 us; speedup vs baseline: 46.1474x; 1.1474x over previous
//
#include <hip/hip_runtime.h>

// RnnTagger (f32 in / f32 out): tokens[64*512] i32; emb[50000,256]; W_ih[1536,256];
// W_hh[1536,512]; b_ih[1536]; b_hh[1536]; W_tag[64,512]; b_tag[64].
// d_out f32: tag_logits [64,512,64] then preds [64,512] flat.
//
// f32-faithful MFMA via f16 double-split: x ~= hi + lo/4096 (hi,lo f16); product
// = 3 f16 MFMAs (m += Ah*Wh; s += Al*Wh + Ah*Wl; result = m + s/4096).
//
// R18 = R11 base (best verified, 6481us total) + per-thread self-gated payload
// loads. R17 post-mortem: per-wave flags REGRESSED (+1.8us/step; 4x flag
// stores + 4x poll slots); __expf proven numerically safe (absmax unchanged).
// R11 budget: hbm_gbps == exchange traffic rate -> every sync hop is an HBM
// round trip; D0's {8-thread poll -> full-WG barrier} gates all 512 threads'
// A-loads behind the SLOWEST flag. Key mapping fact: thread tid's 8 payload
// atoms all satisfy a&255 == tid&255 -> each thread depends on EXACTLY ONE
// producer (jg = (tid&255)>>5). R18:
//  - each thread polls its own producer's flag and issues its A-loads
//    immediately (no D0 barrier); flag-wait and A overlap across threads.
//  - post-E barrier kept (LDS staging visibility before F) -> correctness
//    unchanged; E(t+1) vs F(t) hazards still separated by the post-R and
//    end-of-loop barriers.
//  - fast gates via __expf (R17-proven safe, on the critical G segment).
// Everything else byte-identical to R11 (512-thr WGs, wave-pair K-split,
// 4B pk flag-only exchange, u64 agent atomic payload reads, de-packed LDS
// h planes, single WG-level flag after the drain barrier).
//
// ws (72,482,816 B):
//   [0,+262144)         h pk dbuf  u32[2][64][512]
//   [524288,+3145728)   whh2  [hi/lo][1536][512] f16
//   [3670016,+1572864)  wih2  [hi/lo][1536][256] f16
//   [5242880,+131072)   wtag2 [hi/lo][64][512] f16
//   [5373952,+67108864) st    [b*512+t][512] f32

typedef unsigned short ushortT;
typedef unsigned long long u64c;
typedef float f32x4 __attribute__((ext_vector_type(4)));
typedef _Float16 f16x8 __attribute__((ext_vector_type(8)));
typedef unsigned int u32x4 __attribute__((ext_vector_type(4)));

#define MFMAH(a, b, c) __builtin_amdgcn_mfma_f32_16x16x32_f16((a), (b), (c), 0, 0, 0)
#define KSC (1.0f / 4096.0f)

__device__ __forceinline__ void splitf(float x, ushortT& hi, ushortT& lo) {
    _Float16 h = (_Float16)x;
    float r = x - (float)h;
    _Float16 l = (_Float16)(r * 4096.0f);
    hi = __builtin_bit_cast(ushortT, h);
    lo = __builtin_bit_cast(ushortT, l);
}

__device__ __forceinline__ float fsigmoid(float x) {
    return 1.0f / (1.0f + __expf(-x));     // x->-inf: exp(+inf)=inf -> 0; ok
}
__device__ __forceinline__ float ftanh(float x) {
    const float e2 = __expf(2.0f * x);     // +inf -> 1; 0 -> -1; saturates ok
    return 1.0f - 2.0f / (e2 + 1.0f);
}

// ---------- k0: split weights into f16 hi/lo planes ----------
__global__ __launch_bounds__(256) void split_weights(
    const float* __restrict__ Whh, const float* __restrict__ Wih,
    const float* __restrict__ Wtag, ushortT* __restrict__ wh2,
    ushortT* __restrict__ wi2, ushortT* __restrict__ wt2)
{
    const int i = blockIdx.x * 256 + threadIdx.x;
    ushortT hi, lo;
    if (i < 786432) {                       // 1536*512
        splitf(Whh[i], hi, lo);
        wh2[i] = hi; wh2[786432 + i] = lo;
    } else if (i < 786432 + 393216) {       // 1536*256
        const int j = i - 786432;
        splitf(Wih[j], hi, lo);
        wi2[j] = hi; wi2[393216 + j] = lo;
    } else if (i < 786432 + 393216 + 32768) {   // 64*512
        const int j = i - 786432 - 393216;
        splitf(Wtag[j], hi, lo);
        wt2[j] = hi; wt2[32768 + j] = lo;
    }
}

// ---------- k1: zero h pk double buffer + flags ----------
__global__ void init_ws(uint4* p, uint4* f) {
    int i = blockIdx.x * blockDim.x + threadIdx.x;
    uint4 z; z.x = 0u; z.y = 0u; z.z = 0u; z.w = 0u;
    if (i < 16384) p[i] = z;    // 262144 B / 16
    if (i < 256)   f[i] = z;    // 4096 B of flags
}

// ---------- k2: fused gi + serial GRU recurrence ----------
// 32 WGs x 512 (8 waves = 2 waves/SIMD). cluster = bid>>3 owns batch rows
// [cluster*16,+16); jg = bid&7 owns h-cols [jg*64,+64). Wave pair (w, w+4)
// owns cols jg*64 + w*16 + [0,16), K-split across the pair.
__global__ __launch_bounds__(512, 1) void gru_rec(
    const int* __restrict__ tok, const float* __restrict__ emb,
    const ushortT* __restrict__ wih2, const ushortT* __restrict__ whh2,
    const float* __restrict__ bih, const float* __restrict__ bhh,
    unsigned* __restrict__ hb32, float* __restrict__ st,
    unsigned* __restrict__ flags)
{
    __shared__ ushortT xl[2][2][16][264];   // 33792 B: x dbuf [buf][hi/lo][16 b][256k pad]
    __shared__ ushortT hlh[16 * 520];       // 16640 B: h hi plane [16 rows][512 + pad 8]
    __shared__ ushortT hll[16 * 520];       // 16640 B: h lo plane
    __shared__ f32x4 pl[4][8][64];          // 32768 B: upper-wave partials [u][vec][lane]

    const int bid = blockIdx.x;
    const int cluster = bid >> 3;
    const int jg = bid & 7;
    const int tid = threadIdx.x;
    const int wave = tid >> 6;
    const int lane = tid & 63;
    const int wl = wave & 3;                // pair column-slot 0..3
    const bool upper = wave >= 4;
    const int ln = lane & 15, quad = lane >> 4;
    const int m0 = cluster * 16;
    const int j_lane = jg * 64 + wl * 16 + ln;

    // 128B-padded flags: flags[(cluster*8 + jg)*32]. Each thread polls the ONE
    // producer that owns its payload columns: jg_needed = (tid&255)>>5.
    unsigned* ownp  = flags + (unsigned)(cluster * 8 + jg) * 32u;
    unsigned* pollp = flags + (unsigned)(cluster * 8 + ((tid & 255) >> 5)) * 32u;

    const float c_r  = bih[j_lane]        + bhh[j_lane];
    const float c_z  = bih[512 + j_lane]  + bhh[512 + j_lane];
    const float bi_n = bih[1024 + j_lane];
    const float bh_n = bhh[1024 + j_lane];

    const int fks0 = upper ? 8 : 0;
    const int cks0 = upper ? 4 : 0;

    // Prologue: upper 256 threads stage x_0 into LDS buf 0.
    const int xr = (tid & 255) >> 4, xc = (tid & 15) * 16;
    if (upper) {
        const int token = tok[(m0 + xr) * 512];
        const float* xsrc = emb + (size_t)token * 256 + xc;
#pragma unroll
        for (int i = 0; i < 16; ++i) {
            ushortT hi, lo; splitf(xsrc[i], hi, lo);
            xl[0][0][xr][xc + i] = hi; xl[0][1][xr][xc + i] = lo;
        }
    }
    __syncthreads();

    float hprev[4] = {0.f, 0.f, 0.f, 0.f};

    for (int t = 0; t < 512; ++t) {
        const int rb = t & 1;
        const int wb = rb ^ 1;
        const u64c* tile64 =
            (const u64c*)(hb32 + (size_t)rb * 32768 + (size_t)m0 * 512);

        // (B) upper: x_{t+1} global loads into regs (published in phase H)
        f32x4 xv[4];
        if (upper) {
            const int tp = (t + 1) & 511;
            const int xtoken = tok[(m0 + xr) * 512 + tp];
            const float* xsrc = emb + (size_t)xtoken * 256 + xc;
#pragma unroll
            for (int i = 0; i < 4; ++i)
                xv[i] = *reinterpret_cast<const f32x4*>(xsrc + i * 4);
        }

        // per-pair partial accumulators
        f32x4 m_r = (f32x4){0.f,0.f,0.f,0.f}, s_r = (f32x4){0.f,0.f,0.f,0.f};
        f32x4 m_z = (f32x4){0.f,0.f,0.f,0.f}, s_z = (f32x4){0.f,0.f,0.f,0.f};
        f32x4 m_gin = (f32x4){0.f,0.f,0.f,0.f}, s_gin = (f32x4){0.f,0.f,0.f,0.f};
        f32x4 m_ghn = (f32x4){0.f,0.f,0.f,0.f}, s_ghn = (f32x4){0.f,0.f,0.f,0.f};

        // (C) gi = x_t @ W_ih^T, K-split: lower ks 0..3, upper ks 4..7
#pragma unroll
        for (int ksi = 0; ksi < 4; ++ksi) {
            const int k = (cks0 + ksi) * 32 + quad * 8;
            f16x8 Axh = *reinterpret_cast<const f16x8*>(&xl[rb][0][ln][k]);
            f16x8 Axl = *reinterpret_cast<const f16x8*>(&xl[rb][1][ln][k]);
#pragma unroll
            for (int g = 0; g < 3; ++g) {
                const ushortT* wr = wih2 + (size_t)(g * 512 + j_lane) * 256 + k;
                f16x8 Wh = *reinterpret_cast<const f16x8*>(wr);
                f16x8 Wl = *reinterpret_cast<const f16x8*>(wr + 393216);
                if (g == 0) {
                    m_r = MFMAH(Axh, Wh, m_r);
                    s_r = MFMAH(Axl, Wh, s_r);
                    s_r = MFMAH(Axh, Wl, s_r);
                } else if (g == 1) {
                    m_z = MFMAH(Axh, Wh, m_z);
                    s_z = MFMAH(Axl, Wh, s_z);
                    s_z = MFMAH(Axh, Wl, s_z);
                } else {
                    m_gin = MFMAH(Axh, Wh, m_gin);
                    s_gin = MFMAH(Axl, Wh, s_gin);
                    s_gin = MFMAH(Axh, Wl, s_gin);
                }
            }
        }

        // (D0') per-thread flag wait: each thread gates ONLY on the producer
        // that owns its payload columns, then issues its loads immediately.
        // No barrier here — flag-wait and A overlap across threads.
        {
            const unsigned want = (unsigned)t;
            unsigned f = __hip_atomic_load(pollp, __ATOMIC_RELAXED,
                                           __HIP_MEMORY_SCOPE_AGENT);
            while (f < want) {
                __builtin_amdgcn_s_sleep(2);
                f = __hip_atomic_load(pollp, __ATOMIC_RELAXED,
                                      __HIP_MEMORY_SCOPE_AGENT);
            }
        }

        // (A) payload read: 8 u64 agent-coherent atomic loads per thread,
        // each carrying TWO 4B pk's. All 8 belong to this thread's producer.
        u64c v[8];
#pragma unroll
        for (int j = 0; j < 8; ++j)
            v[j] = __hip_atomic_load(tile64 + tid + 512 * j,
                                     __ATOMIC_RELAXED, __HIP_MEMORY_SCOPE_AGENT);

        // (E) publish DE-PACKED hi/lo planes to LDS: 2 cols per atom,
        // packed u32 writes (4B-aligned since c2 and row stride are even)
#pragma unroll
        for (int j = 0; j < 8; ++j) {
            const int a = tid + 512 * j;        // u64 index in [0,4096)
            const int row = a >> 8;             // 0..15
            const int c2 = (a & 255) * 2;       // 0,2,...,510
            const unsigned lo32 = (unsigned)v[j];
            const unsigned hi32 = (unsigned)(v[j] >> 32);
            *reinterpret_cast<unsigned*>(&hlh[row * 520 + c2]) =
                (lo32 & 0xffffu) | (hi32 << 16);
            *reinterpret_cast<unsigned*>(&hll[row * 520 + c2]) =
                (lo32 >> 16) | (hi32 & 0xffff0000u);
        }
        __syncthreads();   // staging visible to all waves before F

        // (F) gh = h_{t-1} @ W_hh^T, K-split: lower ks 0..7, upper ks 8..15.
        // A-frags: direct b128 from de-packed planes. W: streamed from L2.
#pragma unroll
        for (int ksi = 0; ksi < 8; ++ksi) {
            const int k = (fks0 + ksi) * 32 + quad * 8;
            f16x8 Ah = *reinterpret_cast<const f16x8*>(&hlh[ln * 520 + k]);
            f16x8 Al = *reinterpret_cast<const f16x8*>(&hll[ln * 520 + k]);
#pragma unroll
            for (int g = 0; g < 3; ++g) {
                const ushortT* wr = whh2 + (size_t)(g * 512 + j_lane) * 512 + k;
                f16x8 Wh = *reinterpret_cast<const f16x8*>(wr);
                f16x8 Wl = *reinterpret_cast<const f16x8*>(wr + 786432);
                if (g == 0) {
                    m_r = MFMAH(Ah, Wh, m_r);
                    s_r = MFMAH(Al, Wh, s_r);
                    s_r = MFMAH(Ah, Wl, s_r);
                } else if (g == 1) {
                    m_z = MFMAH(Ah, Wh, m_z);
                    s_z = MFMAH(Al, Wh, s_z);
                    s_z = MFMAH(Ah, Wl, s_z);
                } else {
                    m_ghn = MFMAH(Ah, Wh, m_ghn);
                    s_ghn = MFMAH(Al, Wh, s_ghn);
                    s_ghn = MFMAH(Ah, Wl, s_ghn);
                }
            }
        }

        // (R) upper waves dump partials to LDS (lane-consecutive 16B: conflict-free)
        if (upper) {
            const int u = wave - 4;
            pl[u][0][lane] = m_r;   pl[u][1][lane] = s_r;
            pl[u][2][lane] = m_z;   pl[u][3][lane] = s_z;
            pl[u][4][lane] = m_gin; pl[u][5][lane] = s_gin;
            pl[u][6][lane] = m_ghn; pl[u][7][lane] = s_ghn;
        }
        __syncthreads();

        float hn4[4];
        if (!upper) {
            // combine K-halves
            m_r   += pl[wave][0][lane]; s_r   += pl[wave][1][lane];
            m_z   += pl[wave][2][lane]; s_z   += pl[wave][3][lane];
            m_gin += pl[wave][4][lane]; s_gin += pl[wave][5][lane];
            m_ghn += pl[wave][6][lane]; s_ghn += pl[wave][7][lane];

            // (G) gates + h_new; 4B pk stores (drained by the next barrier)
            unsigned* hw32 = hb32 + (size_t)wb * 32768;
#pragma unroll
            for (int r4 = 0; r4 < 4; ++r4) {
                const float pre_r = m_r[r4] + s_r[r4] * KSC + c_r;
                const float pre_z = m_z[r4] + s_z[r4] * KSC + c_z;
                const float gin   = m_gin[r4] + s_gin[r4] * KSC + bi_n;
                const float ghn   = m_ghn[r4] + s_ghn[r4] * KSC + bh_n;
                const float rr = fsigmoid(pre_r);
                const float zz = fsigmoid(pre_z);
                const float nn = ftanh(gin + rr * ghn);
                const float hn = (1.f - zz) * nn + zz * hprev[r4];
                hprev[r4] = hn;
                hn4[r4] = hn;
                ushortT hi, lo; splitf(hn, hi, lo);
                const unsigned pk = (unsigned)hi | ((unsigned)lo << 16);
                const int b = m0 + quad * 4 + r4;
                __hip_atomic_store(&hw32[b * 512 + j_lane], pk,
                                   __ATOMIC_RELAXED, __HIP_MEMORY_SCOPE_AGENT);
            }
        } else {
            // (H) publish x_{t+1} into LDS buffer wb
#pragma unroll
            for (int i = 0; i < 16; ++i) {
                ushortT hi, lo; splitf(xv[i >> 2][i & 3], hi, lo);
                xl[wb][0][xr][xc + i] = hi; xl[wb][1][xr][xc + i] = lo;
            }
        }

        // barrier: each wave drains its own vmcnt before arriving -> all lower
        // waves' payload stores are at the coherence point; also xl/hl turnover
        __syncthreads();
        if (tid == 0)
            __hip_atomic_store(ownp, (unsigned)(t + 1),
                               __ATOMIC_RELAXED, __HIP_MEMORY_SCOPE_AGENT);

        // st stores — consumed only by k3 after this kernel; off critical path
        if (!upper) {
#pragma unroll
            for (int r4 = 0; r4 < 4; ++r4) {
                const int b = m0 + quad * 4 + r4;
                st[((size_t)b * 512 + t) * 512 + j_lane] = hn4[r4];
            }
        }
    }
}

// ---------- k3: tag logits + argmax + PAD mask (R5-identical) ----------
__global__ __launch_bounds__(256) void tag_argmax(
    const float* __restrict__ st, const ushortT* __restrict__ wtag2,
    const float* __restrict__ btag, const int* __restrict__ tok,
    float* __restrict__ out)
{
    const int wave = threadIdx.x >> 6;
    const int lane = threadIdx.x & 63;
    const int ln = lane & 15, quad = lane >> 4;
    const int mt = blockIdx.x * 4 + wave;   // 0..2047

    const float* arow = st + (size_t)(mt * 16 + ln) * 512;
    f32x4 am[4], as_[4];
#pragma unroll
    for (int ti = 0; ti < 4; ++ti) { am[ti] = (f32x4){0.f,0.f,0.f,0.f}; as_[ti] = (f32x4){0.f,0.f,0.f,0.f}; }

#pragma unroll
    for (int ks = 0; ks < 16; ++ks) {
        const int k = ks * 32 + quad * 8;
        f16x8 Ah, Al;
#pragma unroll
        for (int e = 0; e < 8; ++e) {
            const float x = arow[k + e];
            _Float16 h = (_Float16)x;
            Ah[e] = h;
            Al[e] = (_Float16)((x - (float)h) * 4096.0f);
        }
#pragma unroll
        for (int ti = 0; ti < 4; ++ti) {
            const ushortT* wr = wtag2 + (size_t)(ti * 16 + ln) * 512 + k;
            f16x8 Wh = *reinterpret_cast<const f16x8*>(wr);
            f16x8 Wl = *reinterpret_cast<const f16x8*>(wr + 32768);
            am[ti]  = MFMAH(Ah, Wh, am[ti]);
            as_[ti] = MFMAH(Ah, Wl, as_[ti]);
            as_[ti] = MFMAH(Al, Wh, as_[ti]);
        }
    }

    float vals[4][4];
#pragma unroll
    for (int ti = 0; ti < 4; ++ti) {
        const float bb = btag[ti * 16 + ln];
#pragma unroll
        for (int r = 0; r < 4; ++r) vals[ti][r] = am[ti][r] + as_[ti][r] * KSC + bb;
    }
#pragma unroll
    for (int ti = 0; ti < 4; ++ti)
#pragma unroll
        for (int r = 0; r < 4; ++r) {
            const int row = mt * 16 + quad * 4 + r;
            out[(size_t)row * 64 + ti * 16 + ln] = vals[ti][r];
        }
#pragma unroll
    for (int r = 0; r < 4; ++r) {
        float best = vals[0][r];
        int bc = ln;
#pragma unroll
        for (int ti = 1; ti < 4; ++ti) {
            const float v = vals[ti][r];
            const int c = ti * 16 + ln;
            if (v > best) { best = v; bc = c; }
        }
        for (int off = 1; off < 16; off <<= 1) {
            const float ov = __shfl_xor(best, off);
            const int oc = __shfl_xor(bc, off);
            if (ov > best || (ov == best && oc < bc)) { best = ov; bc = oc; }
        }
        if (ln == 0) {
            const int row = mt * 16 + quad * 4 + r;   // = b*512+t = token idx
            const int token = tok[row];
            const int pred = (token != 0) ? bc : 0;
            out[2097152 + (size_t)row] = (float)pred;
        }
    }
}

extern "C" void kernel_launch(void* const* d_in, const int* in_sizes, int n_in,
                              void* d_out, int out_size, void* d_ws, size_t ws_size,
                              hipStream_t stream) {
    const int*   tokens = (const int*)d_in[0];
    const float* emb    = (const float*)d_in[1];
    const float* Wih    = (const float*)d_in[2];
    const float* Whh    = (const float*)d_in[3];
    const float* bih    = (const float*)d_in[4];
    const float* bhh    = (const float*)d_in[5];
    const float* Wtag   = (const float*)d_in[6];
    const float* btag   = (const float*)d_in[7];

    char* ws = (char*)d_ws;
    unsigned* hb32  = (unsigned*)ws;                 // 262,144 B used
    ushortT*  whh2  = (ushortT*)(ws + 524288);       // 3,145,728 B
    ushortT*  wih2  = (ushortT*)(ws + 3670016);      // 1,572,864 B
    ushortT*  wtag2 = (ushortT*)(ws + 5242880);      // 131,072 B
    float*    stf   = (float*)(ws + 5373952);        // 67,108,864 B (total 72.48 MB)
    float*    out   = (float*)d_out;

    // Sync flags live in d_out's preds region (scratch during gru_rec;
    // tag_argmax rewrites every preds element afterwards). 32 flags, 128B pad.
    unsigned* flags = (unsigned*)(out + 2097152);

    split_weights<<<4736, 256, 0, stream>>>(Whh, Wih, Wtag, whh2, wih2, wtag2);
    init_ws<<<128, 256, 0, stream>>>((uint4*)ws, (uint4*)flags);
    gru_rec<<<32, 512, 0, stream>>>(tokens, emb, wih2, whh2, bih, bhh, hb32, stf, flags);
    tag_argmax<<<512, 256, 0, stream>>>(stf, wtag2, btag, tokens, out);
}